// Round 1
// baseline (196.800 us; speedup 1.0000x reference)
//
#include <hip/hip_runtime.h>
#include <hip/hip_cooperative_groups.h>
#include <math.h>

namespace cg = cooperative_groups;

// B=16, C=512, H=W=62, HW=3844, 9 regions, 5 negs/region, TEMP=0.1, EPS=1e-6.
#define NPAIR 8
#define NREG 9
#define NCH 512
#define HW 3844
#define W62 62
#define NPATCH 9
#define NBLK (NPAIR * NREG)  // 72

// The 9 unique patch base offsets (row*62+col). POS region r uses patch r;
// NEG bases are a subset of the same 9 -> indices below.
__constant__ int PATCH_BASE[9] = {0, 30, 60, 1860, 1890, 1920, 3720, 3750, 3780};
__constant__ int NEG_IDX[9][5] = {
    {1, 3, 4, 2, 6},
    {0, 2, 3, 4, 5},
    {0, 1, 4, 5, 8},
    {0, 1, 4, 6, 7},
    {0, 1, 3, 5, 7},
    {1, 2, 4, 7, 8},
    {0, 3, 4, 7, 8},
    {3, 4, 5, 6, 8},
    {2, 4, 5, 6, 7}};

__device__ __forceinline__ float dot4(const float4& a, const float4& b) {
    return a.x * b.x + a.y * b.y + a.z * b.z + a.w * b.w;
}

__device__ __forceinline__ float wave_sum(float v) {
    #pragma unroll
    for (int off = 32; off > 0; off >>= 1) v += __shfl_down(v, off, 64);
    return v;
}

// One 2x2 patch (two aligned float2 rows) -> float4. All PATCH_BASE offsets
// (and +62 row offsets) are even -> 8B-aligned given 256B-aligned x.
__device__ __forceinline__ float4 ld_patch(const float* p) {
    const float2 a0 = *(const float2*)(p);
    const float2 a1 = *(const float2*)(p + W62);
    return make_float4(a0.x, a0.y, a1.x, a1.y);
}

// Fused kernel: one block per (pair, region). Thread = channel. Each thread
// issues its 24 independent 8B loads up-front (MLP-deep), computes the term
// with the SAME reduction structure as the previous 2-kernel version
// (64-lane shfl + 8-wave LDS), writes per-block partial to ws.
// COOP=true: grid.sync() then block 0 reduces the 72 partials -> out.
template <bool COOP>
__global__ __launch_bounds__(512) void lcl_main(const float* __restrict__ x,
                                                float* __restrict__ ws,
                                                float* __restrict__ out) {
    const int blk = blockIdx.x;  // 0..71
    const int p = blk / NREG;
    const int r = blk % NREG;
    const int c = threadIdx.x;

    const float* x1 = x + (size_t)(2 * p * NCH + c) * HW;
    const float* x2 = x + (size_t)((2 * p + 1) * NCH + c) * HW;

    const float4 v1 = ld_patch(x1 + PATCH_BASE[r]);
    const float4 v2 = ld_patch(x2 + PATCH_BASE[r]);
    float4 n1[5], n2[5];
    #pragma unroll
    for (int j = 0; j < 5; j++) {
        const int q = PATCH_BASE[NEG_IDX[r][j]];
        n1[j] = ld_patch(x1 + q);
        n2[j] = ld_patch(x2 + q);
    }

    const float nv1 = dot4(v1, v1);
    const float nv2 = dot4(v2, v2);
    float s = expf(10.0f * dot4(v1, v2) / fmaxf(sqrtf(nv1 * nv2), 1e-6f));
    float d1 = 0.0f, d2 = 0.0f;
    #pragma unroll
    for (int j = 0; j < 5; j++) {
        const float nn1 = dot4(n1[j], n1[j]);
        const float nn2 = dot4(n2[j], n2[j]);
        d1 += expf(10.0f * dot4(v1, n1[j]) / fmaxf(sqrtf(nv1 * nn1), 1e-6f));
        d1 += expf(10.0f * dot4(v1, n2[j]) / fmaxf(sqrtf(nv1 * nn2), 1e-6f));
        d2 += expf(10.0f * dot4(v2, n2[j]) / fmaxf(sqrtf(nv2 * nn2), 1e-6f));
        d2 += expf(10.0f * dot4(v2, n1[j]) / fmaxf(sqrtf(nv2 * nn1), 1e-6f));
    }

    s = wave_sum(s);
    d1 = wave_sum(d1);
    d2 = wave_sum(d2);

    __shared__ float sm[3][8];
    const int wave = threadIdx.x >> 6;
    const int lane = threadIdx.x & 63;
    if (lane == 0) { sm[0][wave] = s; sm[1][wave] = d1; sm[2][wave] = d2; }
    __syncthreads();
    if (threadIdx.x == 0) {
        float S = 0.0f, D1 = 0.0f, D2 = 0.0f;
        #pragma unroll
        for (int w = 0; w < 8; w++) { S += sm[0][w]; D1 += sm[1][w]; D2 += sm[2][w]; }
        ws[blk] = logf(S + D1) + logf(S + D2) - 2.0f * logf(S);
        __threadfence();  // make ws[blk] visible device-wide before grid sync
    }

    if constexpr (COOP) {
        cg::this_grid().sync();
        if (blk == 0 && threadIdx.x < 64) {  // wave 0 whole -> shfl valid
            float t = ws[threadIdx.x];
            if (threadIdx.x < 8) t += ws[64 + threadIdx.x];
            t = wave_sum(t);
            if (threadIdx.x == 0) out[0] = t * (1.0f / 144.0f);
        }
    }
}

// Fallback final reduce (only used if cooperative launch is rejected).
__global__ __launch_bounds__(64) void lcl_final(const float* __restrict__ ws,
                                                float* __restrict__ out) {
    float t = ws[threadIdx.x];
    if (threadIdx.x < 8) t += ws[64 + threadIdx.x];
    t = wave_sum(t);
    if (threadIdx.x == 0) out[0] = t * (1.0f / 144.0f);
}

extern "C" void kernel_launch(void* const* d_in, const int* in_sizes, int n_in,
                              void* d_out, int out_size, void* d_ws, size_t ws_size,
                              hipStream_t stream) {
    const float* x = (const float*)d_in[0];
    float* out = (float*)d_out;
    float* ws = (float*)d_ws;  // 72 floats of partials

    void* args[] = {(void*)&x, (void*)&ws, (void*)&out};
    hipError_t e = hipLaunchCooperativeKernel(
        reinterpret_cast<void*>(lcl_main<true>), dim3(NBLK), dim3(512), args, 0,
        stream);
    if (e != hipSuccess) {
        // Safe fallback: plain launch + tiny reduce kernel (no grid sync).
        lcl_main<false><<<NBLK, 512, 0, stream>>>(x, ws, out);
        lcl_final<<<1, 64, 0, stream>>>(ws, out);
    }
}

// Round 2
// 171.255 us; speedup vs baseline: 1.1492x; 1.1492x over previous
//
#include <hip/hip_runtime.h>
#include <math.h>

// B=16, C=512, H=W=62, HW=3844, 9 regions, 5 negs/region, TEMP=0.1, EPS=1e-6.
#define NPAIR 8
#define NREG 9
#define NCH 512
#define HW 3844
#define W62 62
#define NPATCH 9
#define NBLK (NPAIR * NREG)  // 72

// The 9 unique patch base offsets (row*62+col). POS region r uses patch r;
// NEG bases are a subset of the same 9 -> indices below.
__constant__ int PATCH_BASE[9] = {0, 30, 60, 1860, 1890, 1920, 3720, 3750, 3780};
__constant__ int NEG_IDX[9][5] = {
    {1, 3, 4, 2, 6},
    {0, 2, 3, 4, 5},
    {0, 1, 4, 5, 8},
    {0, 1, 4, 6, 7},
    {0, 1, 3, 5, 7},
    {1, 2, 4, 7, 8},
    {0, 3, 4, 7, 8},
    {3, 4, 5, 6, 8},
    {2, 4, 5, 6, 7}};

__device__ __forceinline__ float dot4(const float4& a, const float4& b) {
    return a.x * b.x + a.y * b.y + a.z * b.z + a.w * b.w;
}

__device__ __forceinline__ float wave_sum(float v) {
    #pragma unroll
    for (int off = 32; off > 0; off >>= 1) v += __shfl_down(v, off, 64);
    return v;
}

// One 2x2 patch (two aligned float2 rows) -> float4. All PATCH_BASE offsets
// (and +62 row offsets) are even -> 8B-aligned given 256B-aligned x.
__device__ __forceinline__ float4 ld_patch(const float* p) {
    const float2 a0 = *(const float2*)(p);
    const float2 a1 = *(const float2*)(p + W62);
    return make_float4(a0.x, a0.y, a1.x, a1.y);
}

// Fused main kernel: one block per (pair, region). Thread = channel. Each
// thread issues its 24 independent 8B loads up-front (deep MLP), computes its
// term with the SAME per-channel math and reduction order as the verified
// 2-kernel version (64-lane shfl + 8-wave LDS), writes per-block partial.
// NOTE: plain launch only — hipLaunchCooperativeKernel breaks the harness's
// graph capture (round-1 post-mortem: +76 µs input-restore copyBuffer).
__global__ __launch_bounds__(512) void lcl_main(const float* __restrict__ x,
                                                float* __restrict__ ws) {
    const int blk = blockIdx.x;  // 0..71
    const int p = blk / NREG;
    const int r = blk % NREG;
    const int c = threadIdx.x;

    const float* x1 = x + (size_t)(2 * p * NCH + c) * HW;
    const float* x2 = x + (size_t)((2 * p + 1) * NCH + c) * HW;

    const float4 v1 = ld_patch(x1 + PATCH_BASE[r]);
    const float4 v2 = ld_patch(x2 + PATCH_BASE[r]);
    float4 n1[5], n2[5];
    #pragma unroll
    for (int j = 0; j < 5; j++) {
        const int q = PATCH_BASE[NEG_IDX[r][j]];
        n1[j] = ld_patch(x1 + q);
        n2[j] = ld_patch(x2 + q);
    }

    const float nv1 = dot4(v1, v1);
    const float nv2 = dot4(v2, v2);
    float s = expf(10.0f * dot4(v1, v2) / fmaxf(sqrtf(nv1 * nv2), 1e-6f));
    float d1 = 0.0f, d2 = 0.0f;
    #pragma unroll
    for (int j = 0; j < 5; j++) {
        const float nn1 = dot4(n1[j], n1[j]);
        const float nn2 = dot4(n2[j], n2[j]);
        d1 += expf(10.0f * dot4(v1, n1[j]) / fmaxf(sqrtf(nv1 * nn1), 1e-6f));
        d1 += expf(10.0f * dot4(v1, n2[j]) / fmaxf(sqrtf(nv1 * nn2), 1e-6f));
        d2 += expf(10.0f * dot4(v2, n2[j]) / fmaxf(sqrtf(nv2 * nn2), 1e-6f));
        d2 += expf(10.0f * dot4(v2, n1[j]) / fmaxf(sqrtf(nv2 * nn1), 1e-6f));
    }

    s = wave_sum(s);
    d1 = wave_sum(d1);
    d2 = wave_sum(d2);

    __shared__ float sm[3][8];
    const int wave = threadIdx.x >> 6;
    const int lane = threadIdx.x & 63;
    if (lane == 0) { sm[0][wave] = s; sm[1][wave] = d1; sm[2][wave] = d2; }
    __syncthreads();
    if (threadIdx.x == 0) {
        float S = 0.0f, D1 = 0.0f, D2 = 0.0f;
        #pragma unroll
        for (int w = 0; w < 8; w++) { S += sm[0][w]; D1 += sm[1][w]; D2 += sm[2][w]; }
        ws[blk] = logf(S + D1) + logf(S + D2) - 2.0f * logf(S);
    }
}

// Final reduce: one wave sums the 72 partials and writes the scalar output
// (overwrite, so no zero-init / atomic needed).
__global__ __launch_bounds__(64) void lcl_final(const float* __restrict__ ws,
                                                float* __restrict__ out) {
    float t = ws[threadIdx.x];
    if (threadIdx.x < 8) t += ws[64 + threadIdx.x];
    t = wave_sum(t);
    if (threadIdx.x == 0) out[0] = t * (1.0f / 144.0f);
}

extern "C" void kernel_launch(void* const* d_in, const int* in_sizes, int n_in,
                              void* d_out, int out_size, void* d_ws, size_t ws_size,
                              hipStream_t stream) {
    const float* x = (const float*)d_in[0];
    float* out = (float*)d_out;
    float* ws = (float*)d_ws;  // 72 floats of partials

    lcl_main<<<NBLK, 512, 0, stream>>>(x, ws);
    lcl_final<<<1, 64, 0, stream>>>(ws, out);
}

// Round 3
// 157.940 us; speedup vs baseline: 1.2460x; 1.0843x over previous
//
#include <hip/hip_runtime.h>
#include <math.h>

// B=16, C=512, H=W=62, HW=3844, 9 regions, 5 negs/region, TEMP=0.1, EPS=1e-6.
//
// Structure (verified best, 160.0 us): two plain launches.
//   Phase A (gather): dedup-fetch the 36 used pixels per (b,c) plane once
//     (9.4 MB of mandatory cold-HBM lines -- the poison fills flush L3 every
//     iteration) into compact g[b*9+patch][c] float4, full-chip occupancy.
//   Phase B (partial): 72 blocks read L2/L3-resident g (96 KB/block), one
//     atomicAdd per block.
// Round-1/2 post-mortems: cooperative launch breaks graph capture (+76 us
// input-restore per iter); fusing phase B's decomposition directly onto x
// re-fetches each line ~6x cold (~56 MB scattered, 72 blocks) -> +11 us.
#define NPAIR 8
#define NREG 9
#define NCH 512
#define HW 3844
#define W62 62
#define NPATCH 9

// The 9 unique patch base offsets (row*62+col). POS region r uses patch r;
// NEG bases are a subset of the same 9 -> indices below.
__constant__ int PATCH_BASE[9] = {0, 30, 60, 1860, 1890, 1920, 3720, 3750, 3780};
__constant__ int NEG_IDX[9][5] = {
    {1, 3, 4, 2, 6},
    {0, 2, 3, 4, 5},
    {0, 1, 4, 5, 8},
    {0, 1, 4, 6, 7},
    {0, 1, 3, 5, 7},
    {1, 2, 4, 7, 8},
    {0, 3, 4, 7, 8},
    {3, 4, 5, 6, 8},
    {2, 4, 5, 6, 7}};

__device__ __forceinline__ float dot4(const float4& a, const float4& b) {
    return a.x * b.x + a.y * b.y + a.z * b.z + a.w * b.w;
}

__device__ __forceinline__ float wave_sum(float v) {
    #pragma unroll
    for (int off = 32; off > 0; off >>= 1) v += __shfl_down(v, off, 64);
    return v;
}

// Phase A: gather the 36 used pixels of each (b,c) plane into compact layout
// g[b*9+patch][c][4] (channel-major, patch-pixels innermost -> float4 access).
// One thread per (b,patch,c); also zero-inits the output accumulator.
__global__ __launch_bounds__(256) void lcl_gather(const float* __restrict__ x,
                                                  float4* __restrict__ g,
                                                  float* __restrict__ out) {
    const int tid = blockIdx.x * 256 + threadIdx.x;  // 0..73727
    if (tid == 0) out[0] = 0.0f;  // ordered before lcl_partial (same stream)
    const int c = tid & (NCH - 1);
    const int bp = tid >> 9;  // b*9 + patch
    const int patch = bp % NPATCH;
    const int b = bp / NPATCH;
    const float* src = x + (size_t)(b * NCH + c) * HW + PATCH_BASE[patch];
    const float2 a0 = *(const float2*)(src);
    const float2 a1 = *(const float2*)(src + W62);
    g[(size_t)bp * NCH + c] = make_float4(a0.x, a0.y, a1.x, a1.y);
}

// Phase B: one block per (pair, region), thread = channel. 12 coalesced
// float4 loads per thread from L2/L3-resident g; atomicAdd one term per block.
__global__ __launch_bounds__(512) void lcl_partial(const float4* __restrict__ g,
                                                   float* __restrict__ out) {
    const int blk = blockIdx.x;  // 0..71
    const int p = blk / NREG;
    const int r = blk % NREG;
    const int c = threadIdx.x;

    const float4* g1 = g + (size_t)(2 * p) * NPATCH * NCH + c;
    const float4* g2 = g + (size_t)(2 * p + 1) * NPATCH * NCH + c;

    const float4 v1 = g1[r * NCH];
    const float4 v2 = g2[r * NCH];
    const float nv1 = dot4(v1, v1);
    const float nv2 = dot4(v2, v2);

    float s = expf(10.0f * dot4(v1, v2) / fmaxf(sqrtf(nv1 * nv2), 1e-6f));
    float d1 = 0.0f, d2 = 0.0f;
    #pragma unroll
    for (int j = 0; j < 5; j++) {
        const int q = NEG_IDX[r][j];
        const float4 n1 = g1[q * NCH];
        const float4 n2 = g2[q * NCH];
        const float nn1 = dot4(n1, n1);
        const float nn2 = dot4(n2, n2);
        d1 += expf(10.0f * dot4(v1, n1) / fmaxf(sqrtf(nv1 * nn1), 1e-6f));
        d1 += expf(10.0f * dot4(v1, n2) / fmaxf(sqrtf(nv1 * nn2), 1e-6f));
        d2 += expf(10.0f * dot4(v2, n2) / fmaxf(sqrtf(nv2 * nn2), 1e-6f));
        d2 += expf(10.0f * dot4(v2, n1) / fmaxf(sqrtf(nv2 * nn1), 1e-6f));
    }

    s = wave_sum(s);
    d1 = wave_sum(d1);
    d2 = wave_sum(d2);

    __shared__ float sm[3][8];
    const int wave = threadIdx.x >> 6;
    const int lane = threadIdx.x & 63;
    if (lane == 0) { sm[0][wave] = s; sm[1][wave] = d1; sm[2][wave] = d2; }
    __syncthreads();
    if (threadIdx.x == 0) {
        float S = 0.0f, D1 = 0.0f, D2 = 0.0f;
        #pragma unroll
        for (int w = 0; w < 8; w++) { S += sm[0][w]; D1 += sm[1][w]; D2 += sm[2][w]; }
        const float term = logf(S + D1) + logf(S + D2) - 2.0f * logf(S);
        atomicAdd(out, term * (1.0f / 144.0f));
    }
}

extern "C" void kernel_launch(void* const* d_in, const int* in_sizes, int n_in,
                              void* d_out, int out_size, void* d_ws, size_t ws_size,
                              hipStream_t stream) {
    const float* x = (const float*)d_in[0];
    float* out = (float*)d_out;
    float4* g = (float4*)d_ws;  // 16*9*512 float4 = 1.18 MB

    lcl_gather<<<(16 * NPATCH * NCH) / 256, 256, 0, stream>>>(x, g, out);
    lcl_partial<<<NPAIR * NREG, 512, 0, stream>>>(g, out);
}